// Round 10
// baseline (1144.888 us; speedup 1.0000x reference)
//
#include <hip/hip_runtime.h>
#include <cstddef>
#include <cstdint>

// Problem constants (fixed-shape problem)
#define DD   128      // feature dim
#define PP   8192     // nodes per level
#define KK   8        // in-edges per node
#define LLV  16       // levels
#define NN   131072   // total nodes
#define NE   65536    // edges per level (PP*KK)
#define NLVL 15       // levels with edges

typedef _Float16 h8 __attribute__((ext_vector_type(8)));
typedef _Float16 h4 __attribute__((ext_vector_type(4)));
typedef float f4v __attribute__((ext_vector_type(4)));

__device__ __forceinline__ float4 ld4(const float* p) { return *(const float4*)p; }
__device__ __forceinline__ void st4(float* p, float4 v) { *(float4*)p = v; }

// XOR swizzle for f16 [row][128] LDS arrays read as h8 (ds_read_b128).
__device__ __forceinline__ int swz(int row, int k) { return row * 128 + (k ^ ((row & 7) << 3)); }

// Store a float4 as 4 contiguous (swizzled) f16 halves (activation f16 is
// numerically free here: absmax pinned at 2^-7 across rounds 2-9).
__device__ __forceinline__ void hstore4(_Float16* ah, int row, int k0, float4 v) {
  int o = swz(row, k0);
  h4 hi;
  hi[0] = (_Float16)v.x; hi[1] = (_Float16)v.y;
  hi[2] = (_Float16)v.z; hi[3] = (_Float16)v.w;
  *(h4*)(ah + o) = hi;
}

// Load B-fragments for ONE 16-col tile (4 k-slices, hi+lo): 8 coalesced
// global_load_dwordx4 -> 32 VGPRs. L2-hot (same 64KB image for all blocks).
__device__ __forceinline__ void load_bfrags1(const _Float16* __restrict__ img, int t16, int lane,
                                             h8 Bh[4], h8 Bl[4]) {
#pragma unroll
  for (int ks = 0; ks < 4; ks++) {
    int o = ((t16 * 4 + ks) * 64 + lane) * 8;
    Bh[ks] = *(const h8*)(img + o);
    Bl[ks] = *(const h8*)(img + 16384 + o);
  }
}

// One 16-row x 16-col output tile: A (f16) from swizzled LDS, B (hi/lo) from regs.
// 2-pass: Ah*(Bh+Bl) ~ full weight precision, fp32 accumulate.
// Dual accumulator: two 4-deep dependent MFMA chains instead of one 8-deep.
__device__ __forceinline__ f4v gemm_rt(const _Float16* __restrict__ ah,
                                       const h8 Bh[4], const h8 Bl[4], int rbase, int lane) {
  int r16 = lane & 15, kb = lane >> 4;
  int arow = rbase + r16;
  h8 Ah[4];
#pragma unroll
  for (int ks = 0; ks < 4; ks++) Ah[ks] = *(const h8*)(ah + swz(arow, ks * 32 + kb * 8));
  f4v a0 = {0.f, 0.f, 0.f, 0.f};
  f4v a1 = {0.f, 0.f, 0.f, 0.f};
#pragma unroll
  for (int ks = 0; ks < 2; ks++) {
    a0 = __builtin_amdgcn_mfma_f32_16x16x32_f16(Ah[ks], Bh[ks], a0, 0, 0, 0);
    a1 = __builtin_amdgcn_mfma_f32_16x16x32_f16(Ah[ks + 2], Bh[ks + 2], a1, 0, 0, 0);
  }
#pragma unroll
  for (int ks = 0; ks < 2; ks++) {
    a0 = __builtin_amdgcn_mfma_f32_16x16x32_f16(Ah[ks], Bl[ks], a0, 0, 0, 0);
    a1 = __builtin_amdgcn_mfma_f32_16x16x32_f16(Ah[ks + 2], Bl[ks + 2], a1, 0, 0, 0);
  }
  return a0 + a1;
}

// ---------------- Fused setup: weight prep (blocks 0-11) + per-level CSR (blocks 12-26) ----
// CSR edges pack local destination row: edges[pos] = p | ((q & 31) << 16).
__global__ __launch_bounds__(1024) void setup_kernel(
    const float* __restrict__ w0, const float* __restrict__ w1,
    const float* __restrict__ w2, const float* __restrict__ w3,
    const float* __restrict__ w4, const float* __restrict__ w5,
    _Float16* __restrict__ img_base,
    const int* __restrict__ src_all,
    int* __restrict__ offs, int* __restrict__ edges) {
  int t = threadIdx.x;
  if (blockIdx.x < 12) {
    int mat = blockIdx.x >> 1;
    int g = (blockIdx.x & 1) * 1024 + t;   // 0..2047
    const float* w;
    switch (mat) {
      case 0: w = w0; break;
      case 1: w = w1; break;
      case 2: w = w2; break;
      case 3: w = w3; break;
      case 4: w = w4; break;
      default: w = w5; break;
    }
    _Float16* img = img_base + (size_t)mat * 32768;
    int t16 = g >> 8, ks = (g >> 6) & 3, lane = g & 63;
    int n = t16 * 16 + (lane & 15);
    int kb = ks * 32 + (lane >> 4) * 8;
    h8 hi, lo;
#pragma unroll
    for (int j = 0; j < 8; j++) {
      float v = w[(kb + j) * 128 + n];
      _Float16 h = (_Float16)v;
      hi[j] = h;
      lo[j] = (_Float16)(v - (float)h);
    }
    int o = ((t16 * 4 + ks) * 64 + lane) * 8;
    *(h8*)(img + o) = hi;
    *(h8*)(img + 16384 + o) = lo;
  } else {
    int l = blockIdx.x - 12;
    const int* src = src_all + (size_t)l * NE;
    __shared__ int cnt[PP];        // 32 KB
    __shared__ int bsum[1024];
#pragma unroll
    for (int j = 0; j < 8; j++) cnt[t + j * 1024] = 0;
    __syncthreads();
#pragma unroll 4
    for (int j = 0; j < 64; j++) {
      int q = src[j * 1024 + t];
      atomicAdd(&cnt[q], 1);
    }
    __syncthreads();
    int loc[8];
    int s = 0;
#pragma unroll
    for (int j = 0; j < 8; j++) { loc[j] = cnt[t * 8 + j]; s += loc[j]; }
    bsum[t] = s;
    __syncthreads();
    for (int off = 1; off < 1024; off <<= 1) {
      int v = (t >= off) ? bsum[t - off] : 0;
      __syncthreads();
      bsum[t] += v;
      __syncthreads();
    }
    int run = (t == 0) ? 0 : bsum[t - 1];
#pragma unroll
    for (int j = 0; j < 8; j++) {
      offs[l * (PP + 1) + t * 8 + j] = run;
      cnt[t * 8 + j] = run;
      run += loc[j];
    }
    if (t == 1023) offs[l * (PP + 1) + PP] = run;
    __syncthreads();
#pragma unroll 4
    for (int j = 0; j < 64; j++) {
      int e = j * 1024 + t;
      int q = src[e];
      int pos = atomicAdd(&cnt[q], 1);
      edges[(size_t)l * NE + pos] = (e >> 3) | ((q & 31) << 16);
    }
  }
}

// ---------------- Node transform + fused step-0 of both directions ----------------
__global__ __launch_bounds__(512, 4) void nt_kernel(
    const float* __restrict__ x,
    const _Float16* __restrict__ w1img, const float* __restrict__ b1,
    const _Float16* __restrict__ w2img, const float* __restrict__ b2,
    float* __restrict__ hout,
    const float* __restrict__ f_upd_b, const _Float16* __restrict__ f_pre_img,
    const float* __restrict__ f_pre_b,
    const float* __restrict__ b_upd_b, const _Float16* __restrict__ b_pre_img,
    const float* __restrict__ b_pre_b,
    _Float16* __restrict__ mf0, _Float16* __restrict__ mb0,
    float* __restrict__ out) {
  __shared__ __align__(16) _Float16 abuf0[8192];  // 16 KB: x, later u0
  __shared__ __align__(16) _Float16 abuf1[8192];  // 16 KB: t1
  int tid = threadIdx.x;
  int lane = tid & 63, wv = tid >> 6;             // wv = col-tile 0..7
  int r16 = lane & 15, kb = lane >> 4;
  int colg = wv * 16 + r16;                       // this lane's D column
  size_t base = (size_t)blockIdx.x * 64;

  h8 Bh[4], Bl[4];
  load_bfrags1(w1img, wv, lane, Bh, Bl);

#pragma unroll
  for (int j = 0; j < 4; j++) {
    int s = tid + j * 512;
    float4 v = ((const float4*)(x + base * 128))[s];
    hstore4(abuf0, s >> 5, (s & 31) * 4, v);
  }
  __syncthreads();                                // bar1: x staged

  f4v acc[4];
#pragma unroll
  for (int rt = 0; rt < 4; rt++) acc[rt] = gemm_rt(abuf0, Bh, Bl, rt * 16, lane);
  load_bfrags1(w2img, wv, lane, Bh, Bl);
  {
    float b = b1[colg];
#pragma unroll
    for (int rt = 0; rt < 4; rt++)
#pragma unroll
      for (int r = 0; r < 4; r++)
        abuf1[swz(rt * 16 + kb * 4 + r, colg)] = (_Float16)fmaxf(acc[rt][r] + b, 0.f);
  }
  __syncthreads();                                // bar2: t1 ready

#pragma unroll
  for (int rt = 0; rt < 4; rt++) acc[rt] = gemm_rt(abuf1, Bh, Bl, rt * 16, lane);
  float b2s = b2[colg];
#pragma unroll
  for (int rt = 0; rt < 4; rt++)
#pragma unroll
    for (int r = 0; r < 4; r++) {
      int row = rt * 16 + kb * 4 + r;
      hout[(base + row) * 128 + colg] = acc[rt][r] + b2s;   // D-layout scalar store
    }

  // ---- fused step 0: level-0 (fwd) / level-15 (bwd) blocks; h still in acc ----
  bool lvl0 = (blockIdx.x < 128);
  bool lvl15 = (blockIdx.x >= 1920);
  if (lvl0 || lvl15) {
    const float* ub = lvl0 ? f_upd_b : b_upd_b;
    const _Float16* pimg = lvl0 ? f_pre_img : b_pre_img;
    const float* pb = lvl0 ? f_pre_b : b_pre_b;
    _Float16* mdst = lvl0 ? mf0 : mb0;
    int coloff = lvl0 ? 0 : 128;
    size_t lbase = lvl0 ? 0 : (size_t)15 * PP;    // node base of the level

    float rb = fmaxf(ub[colg], 0.f);
#pragma unroll
    for (int rt = 0; rt < 4; rt++)
#pragma unroll
      for (int r = 0; r < 4; r++) {
        int row = rt * 16 + kb * 4 + r;
        float u0 = (acc[rt][r] + b2s) + rb;       // h + relu(upd_b)
        out[(base + row) * 256 + coloff + colg] = u0;
        abuf0[swz(row, colg)] = (_Float16)u0;     // abuf0 free after GEMM1
      }
    load_bfrags1(pimg, wv, lane, Bh, Bl);
    __syncthreads();                              // bar3: u0 ready
#pragma unroll
    for (int rt = 0; rt < 4; rt++) acc[rt] = gemm_rt(abuf0, Bh, Bl, rt * 16, lane);
    float pbs = pb[colg];
#pragma unroll
    for (int rt = 0; rt < 4; rt++)
#pragma unroll
      for (int r = 0; r < 4; r++) {
        int row = rt * 16 + kb * 4 + r;
        float m = fmaxf(acc[rt][r] + pbs, 0.f);
        mdst[(base + row - lbase) * 128 + colg] = (_Float16)m;
      }
  }
}

// ---------------- Fused message-passing step (s in 1..15) ----------------
// grid = 512: blocks 0..255 = forward level s, 256..511 = reverse level 15-s.
// Forward: fixed-degree-8 per-row gather (balanced). Reverse: edge-balanced
// gather over the tile's contiguous CSR range via LDS f32 atomics (removes the
// worst-row serial tail that set the block's critical path).
__global__ __launch_bounds__(512, 4) void mp_step(
    const float* __restrict__ h,
    const int* __restrict__ src_all,
    const int* __restrict__ offs,
    const int* __restrict__ edges,
    const _Float16* __restrict__ fw_upd_img, const float* __restrict__ fw_upd_b,
    const _Float16* __restrict__ fw_pre_img, const float* __restrict__ fw_pre_b,
    const _Float16* __restrict__ bw_upd_img, const float* __restrict__ bw_upd_b,
    const _Float16* __restrict__ bw_pre_img, const float* __restrict__ bw_pre_b,
    const _Float16* __restrict__ mf_in, _Float16* __restrict__ mf_out,
    const _Float16* __restrict__ mb_in, _Float16* __restrict__ mb_out,
    float* __restrict__ out, int step) {
  __shared__ __align__(16) _Float16 abuf0[4096];  // 8 KB: z (f16)
  __shared__ __align__(16) _Float16 abuf1[4096];  // 8 KB: u (f16)
  __shared__ __align__(16) float zbuf[4096];      // 16 KB: reverse z accumulator
  int tid = threadIdx.x;
  int lane = tid & 63, wv = tid >> 6;             // wv = col-tile 0..7
  int c4 = tid & 31, rg2 = (tid >> 5) * 2;        // rows 0..30, 2 per thread
  int r16 = lane & 15, kb = lane >> 4;
  int colg = wv * 16 + r16;                       // this lane's D column
  bool is_fwd = blockIdx.x < 256;
  int tile = (blockIdx.x & 255) * 32;
  int level = is_fwd ? step : 15 - step;
  const _Float16* upd_img = is_fwd ? fw_upd_img : bw_upd_img;
  const float* upd_b = is_fwd ? fw_upd_b : bw_upd_b;
  const _Float16* pre_img = is_fwd ? fw_pre_img : bw_pre_img;
  const float* pre_b = is_fwd ? fw_pre_b : bw_pre_b;
  const _Float16* m_in = is_fwd ? mf_in : mb_in;
  _Float16* m_out      = is_fwd ? mf_out : mb_out;
  bool has_mout = (step < 15);
  int col_off = is_fwd ? 0 : 128;

  // h residuals hoisted: latency hides under the gather + GEMM1.
  float hreg[2][4];
#pragma unroll
  for (int rt = 0; rt < 2; rt++)
#pragma unroll
    for (int r = 0; r < 4; r++) {
      int row = rt * 16 + kb * 4 + r;
      hreg[rt][r] = h[((size_t)level * PP + tile + row) * 128 + colg];
    }

  // B-fragments for the update GEMM: latency overlaps the gather.
  h8 BhU[4], BlU[4];
  load_bfrags1(upd_img, wv, lane, BhU, BlU);

  // ---- phase A: gather z -> abuf0 ----
  if (is_fwd) {
    const int* src = src_all + (size_t)(step - 1) * NE;
#pragma unroll
    for (int i = 0; i < 2; i++) {
      int r = rg2 + i;
      int p = tile + r;
      const int4* sp = (const int4*)(src + p * 8);
      int4 s0 = sp[0], s1 = sp[1];
      h4 v0 = *(const h4*)(m_in + (size_t)s0.x * 128 + c4 * 4);
      h4 v1 = *(const h4*)(m_in + (size_t)s0.y * 128 + c4 * 4);
      h4 v2 = *(const h4*)(m_in + (size_t)s0.z * 128 + c4 * 4);
      h4 v3 = *(const h4*)(m_in + (size_t)s0.w * 128 + c4 * 4);
      h4 v4 = *(const h4*)(m_in + (size_t)s1.x * 128 + c4 * 4);
      h4 v5 = *(const h4*)(m_in + (size_t)s1.y * 128 + c4 * 4);
      h4 v6 = *(const h4*)(m_in + (size_t)s1.z * 128 + c4 * 4);
      h4 v7 = *(const h4*)(m_in + (size_t)s1.w * 128 + c4 * 4);
      float4 a;
      a.x = (((float)v0[0] + (float)v1[0]) + ((float)v2[0] + (float)v3[0])) +
            (((float)v4[0] + (float)v5[0]) + ((float)v6[0] + (float)v7[0]));
      a.y = (((float)v0[1] + (float)v1[1]) + ((float)v2[1] + (float)v3[1])) +
            (((float)v4[1] + (float)v5[1]) + ((float)v6[1] + (float)v7[1]));
      a.z = (((float)v0[2] + (float)v1[2]) + ((float)v2[2] + (float)v3[2])) +
            (((float)v4[2] + (float)v5[2]) + ((float)v6[2] + (float)v7[2]));
      a.w = (((float)v0[3] + (float)v1[3]) + ((float)v2[3] + (float)v3[3])) +
            (((float)v4[3] + (float)v5[3]) + ((float)v6[3] + (float)v7[3]));
      a.x *= 0.125f; a.y *= 0.125f; a.z *= 0.125f; a.w *= 0.125f;
      hstore4(abuf0, r, c4 * 4, a);
    }
    __syncthreads();                              // bar1: z ready
  } else {
    // zero the z accumulator tile (each thread zeroes its 2 rows x 4 cols)
#pragma unroll
    for (int i = 0; i < 2; i++)
      *(float4*)(zbuf + (rg2 + i) * 128 + c4 * 4) = float4{0.f, 0.f, 0.f, 0.f};
    __syncthreads();                              // zbuf zeroed

    const int* off_l = offs + level * (PP + 1);
    const int* ep = edges + level * NE;
    int e0b = off_l[tile], e1b = off_l[tile + 32];
    int cnt = e1b - e0b;
    int slot = tid >> 5;                          // 0..15
    int per = (cnt + 15) >> 4;
    int ea = e0b + slot * per;
    int eb = ea + per; if (eb > e1b) eb = e1b;
    int e = ea;
    for (; e + 4 <= eb; e += 4) {
      int v0i = ep[e], v1i = ep[e + 1], v2i = ep[e + 2], v3i = ep[e + 3];
      h4 m0 = *(const h4*)(m_in + (size_t)(v0i & 0xFFFF) * 128 + c4 * 4);
      h4 m1 = *(const h4*)(m_in + (size_t)(v1i & 0xFFFF) * 128 + c4 * 4);
      h4 m2 = *(const h4*)(m_in + (size_t)(v2i & 0xFFFF) * 128 + c4 * 4);
      h4 m3 = *(const h4*)(m_in + (size_t)(v3i & 0xFFFF) * 128 + c4 * 4);
      int b0 = (v0i >> 16) * 128 + c4 * 4;
      int b1 = (v1i >> 16) * 128 + c4 * 4;
      int b2 = (v2i >> 16) * 128 + c4 * 4;
      int b3 = (v3i >> 16) * 128 + c4 * 4;
#pragma unroll
      for (int j = 0; j < 4; j++) {
        atomicAdd(&zbuf[b0 + j], (float)m0[j]);
        atomicAdd(&zbuf[b1 + j], (float)m1[j]);
        atomicAdd(&zbuf[b2 + j], (float)m2[j]);
        atomicAdd(&zbuf[b3 + j], (float)m3[j]);
      }
    }
    for (; e < eb; e++) {
      int vi = ep[e];
      h4 m = *(const h4*)(m_in + (size_t)(vi & 0xFFFF) * 128 + c4 * 4);
      int b = (vi >> 16) * 128 + c4 * 4;
#pragma unroll
      for (int j = 0; j < 4; j++) atomicAdd(&zbuf[b + j], (float)m[j]);
    }
    __syncthreads();                              // all atomics done

    // finalize: mean + convert to f16 A-tile
#pragma unroll
    for (int i = 0; i < 2; i++) {
      int r = rg2 + i;
      int q = tile + r;
      int deg = off_l[q + 1] - off_l[q];
      float inv = (deg > 0) ? 1.0f / (float)deg : 0.f;
      float4 a = *(const float4*)(zbuf + r * 128 + c4 * 4);
      a.x *= inv; a.y *= inv; a.z *= inv; a.w *= inv;
      hstore4(abuf0, r, c4 * 4, a);
    }
    __syncthreads();                              // bar1: z ready
  }

  // ---- phase B: u = relu(z@upd_w + upd_b) + h; direct D-layout epilogue ----
  f4v acc[2];
#pragma unroll
  for (int rt = 0; rt < 2; rt++) acc[rt] = gemm_rt(abuf0, BhU, BlU, rt * 16, lane);
  {
    float ubs = upd_b[colg];
#pragma unroll
    for (int rt = 0; rt < 2; rt++)
#pragma unroll
      for (int r = 0; r < 4; r++) {
        int row = rt * 16 + kb * 4 + r;
        size_t n = (size_t)level * PP + tile + row;
        float uval = fmaxf(acc[rt][r] + ubs, 0.f) + hreg[rt][r];
        out[n * 256 + col_off + colg] = uval;
        abuf1[swz(row, colg)] = (_Float16)uval;
      }
  }

  // ---- phase C: m_out = relu(u @ pre_w + pre_b), direct D-layout f16 store ----
  if (has_mout) {
    h8 BhP[4], BlP[4];
    load_bfrags1(pre_img, wv, lane, BhP, BlP);
    __syncthreads();                              // bar2: u ready
#pragma unroll
    for (int rt = 0; rt < 2; rt++) acc[rt] = gemm_rt(abuf1, BhP, BlP, rt * 16, lane);
    float pbs = pre_b[colg];
#pragma unroll
    for (int rt = 0; rt < 2; rt++)
#pragma unroll
      for (int r = 0; r < 4; r++) {
        int row = rt * 16 + kb * 4 + r;
        float m = fmaxf(acc[rt][r] + pbs, 0.f);
        m_out[(size_t)(tile + row) * 128 + colg] = (_Float16)m;
      }
  }
}

extern "C" void kernel_launch(void* const* d_in, const int* in_sizes, int n_in,
                              void* d_out, int out_size, void* d_ws, size_t ws_size,
                              hipStream_t stream) {
  const float* x      = (const float*)d_in[0];
  const int*   src    = (const int*)d_in[1];
  const float* nt_w1  = (const float*)d_in[2];
  const float* nt_b1  = (const float*)d_in[3];
  const float* nt_w2  = (const float*)d_in[4];
  const float* nt_b2  = (const float*)d_in[5];
  const float* f_pre_w = (const float*)d_in[6];
  const float* f_pre_b = (const float*)d_in[7];
  const float* f_upd_w = (const float*)d_in[8];
  const float* f_upd_b = (const float*)d_in[9];
  const float* b_pre_w = (const float*)d_in[10];
  const float* b_pre_b = (const float*)d_in[11];
  const float* b_upd_w = (const float*)d_in[12];
  const float* b_upd_b = (const float*)d_in[13];
  float* out = (float*)d_out;

  float* wsf = (float*)d_ws;
  float* h   = wsf;                                  // NN*DD f32
  _Float16* mf0 = (_Float16*)(h + (size_t)NN * DD);  // PP*DD f16 each
  _Float16* mf1 = mf0 + (size_t)PP * DD;
  _Float16* mb0 = mf1 + (size_t)PP * DD;
  _Float16* mb1 = mb0 + (size_t)PP * DD;
  int* offs   = (int*)(mb1 + (size_t)PP * DD);       // NLVL*(PP+1)
  int* edges  = offs + NLVL * (PP + 1);              // NLVL*NE

  // fragment-ordered f16 hi/lo weight images (32768 halves = 64KB each)
  uintptr_t ip = (uintptr_t)(edges + (size_t)NLVL * NE);
  ip = (ip + 15) & ~(uintptr_t)15;
  _Float16* img = (_Float16*)ip;
  _Float16* i_ntw1 = img;                 // mat 0
  _Float16* i_ntw2 = img + 32768;         // mat 1
  _Float16* i_fupd = img + 2 * 32768;     // mat 2
  _Float16* i_fpre = img + 3 * 32768;     // mat 3
  _Float16* i_bupd = img + 4 * 32768;     // mat 4
  _Float16* i_bpre = img + 5 * 32768;     // mat 5

  setup_kernel<<<27, 1024, 0, stream>>>(nt_w1, nt_w2, f_upd_w, f_pre_w, b_upd_w, b_pre_w,
                                        img, src, offs, edges);
  nt_kernel<<<NN / 64, 512, 0, stream>>>(x, i_ntw1, nt_b1, i_ntw2, nt_b2, h,
                                         f_upd_b, i_fpre, f_pre_b,
                                         b_upd_b, i_bpre, b_pre_b,
                                         mf0, mb0, out);

  for (int s = 1; s < 16; s++) {
    const _Float16* mf_in = (s & 1) ? mf0 : mf1;
    _Float16* mf_out      = (s & 1) ? mf1 : mf0;
    const _Float16* mb_in = (s & 1) ? mb0 : mb1;
    _Float16* mb_out      = (s & 1) ? mb1 : mb0;
    mp_step<<<512, 512, 0, stream>>>(h, src, offs, edges,
                                     i_fupd, f_upd_b, i_fpre, f_pre_b,
                                     i_bupd, b_upd_b, i_bpre, b_pre_b,
                                     mf_in, mf_out, mb_in, mb_out, out, s);
  }
}

// Round 11
// 522.151 us; speedup vs baseline: 2.1926x; 2.1926x over previous
//
#include <hip/hip_runtime.h>
#include <cstddef>
#include <cstdint>

// Problem constants (fixed-shape problem)
#define DD   128      // feature dim
#define PP   8192     // nodes per level
#define KK   8        // in-edges per node
#define LLV  16       // levels
#define NN   131072   // total nodes
#define NE   65536    // edges per level (PP*KK)
#define NLVL 15       // levels with edges

typedef _Float16 h8 __attribute__((ext_vector_type(8)));
typedef _Float16 h4 __attribute__((ext_vector_type(4)));
typedef float f4v __attribute__((ext_vector_type(4)));

__device__ __forceinline__ float4 ld4(const float* p) { return *(const float4*)p; }
__device__ __forceinline__ void st4(float* p, float4 v) { *(float4*)p = v; }

// XOR swizzle for f16 [row][128] LDS arrays read as h8 (ds_read_b128).
__device__ __forceinline__ int swz(int row, int k) { return row * 128 + (k ^ ((row & 7) << 3)); }
// XOR swizzle for f32 [row][128] scratch (nt only).
__device__ __forceinline__ int uswz(int row, int c) { return row * 128 + (c ^ ((row & 7) << 2)); }

// Store a float4 as 4 contiguous (swizzled) f16 halves (activation f16 is
// numerically free here: absmax pinned at 2^-7 across rounds 2-10).
__device__ __forceinline__ void hstore4(_Float16* ah, int row, int k0, float4 v) {
  int o = swz(row, k0);
  h4 hi;
  hi[0] = (_Float16)v.x; hi[1] = (_Float16)v.y;
  hi[2] = (_Float16)v.z; hi[3] = (_Float16)v.w;
  *(h4*)(ah + o) = hi;
}

// Load B-fragments for ONE 16-col tile (4 k-slices, hi+lo): 8 coalesced
// global_load_dwordx4 -> 32 VGPRs. L2-hot (same 64KB image for all blocks).
__device__ __forceinline__ void load_bfrags1(const _Float16* __restrict__ img, int t16, int lane,
                                             h8 Bh[4], h8 Bl[4]) {
#pragma unroll
  for (int ks = 0; ks < 4; ks++) {
    int o = ((t16 * 4 + ks) * 64 + lane) * 8;
    Bh[ks] = *(const h8*)(img + o);
    Bl[ks] = *(const h8*)(img + 16384 + o);
  }
}

// One 16-row x 16-col output tile: A (f16) from swizzled LDS, B (hi/lo) from regs.
// 2-pass: Ah*(Bh+Bl) ~ full weight precision, fp32 accumulate.
__device__ __forceinline__ f4v gemm_rt(const _Float16* __restrict__ ah,
                                       const h8 Bh[4], const h8 Bl[4], int rbase, int lane) {
  int r16 = lane & 15, kb = lane >> 4;
  int arow = rbase + r16;
  h8 Ah[4];
#pragma unroll
  for (int ks = 0; ks < 4; ks++) Ah[ks] = *(const h8*)(ah + swz(arow, ks * 32 + kb * 8));
  f4v a = {0.f, 0.f, 0.f, 0.f};
#pragma unroll
  for (int ks = 0; ks < 4; ks++) a = __builtin_amdgcn_mfma_f32_16x16x32_f16(Ah[ks], Bh[ks], a, 0, 0, 0);
#pragma unroll
  for (int ks = 0; ks < 4; ks++) a = __builtin_amdgcn_mfma_f32_16x16x32_f16(Ah[ks], Bl[ks], a, 0, 0, 0);
  return a;
}

// ---------------- Fused setup: weight prep (blocks 0-11) + per-level CSR (blocks 12-26) ----
__global__ __launch_bounds__(1024) void setup_kernel(
    const float* __restrict__ w0, const float* __restrict__ w1,
    const float* __restrict__ w2, const float* __restrict__ w3,
    const float* __restrict__ w4, const float* __restrict__ w5,
    _Float16* __restrict__ img_base,
    const int* __restrict__ src_all,
    int* __restrict__ offs, int* __restrict__ edges) {
  int t = threadIdx.x;
  if (blockIdx.x < 12) {
    int mat = blockIdx.x >> 1;
    int g = (blockIdx.x & 1) * 1024 + t;   // 0..2047
    const float* w;
    switch (mat) {
      case 0: w = w0; break;
      case 1: w = w1; break;
      case 2: w = w2; break;
      case 3: w = w3; break;
      case 4: w = w4; break;
      default: w = w5; break;
    }
    _Float16* img = img_base + (size_t)mat * 32768;
    int t16 = g >> 8, ks = (g >> 6) & 3, lane = g & 63;
    int n = t16 * 16 + (lane & 15);
    int kb = ks * 32 + (lane >> 4) * 8;
    h8 hi, lo;
#pragma unroll
    for (int j = 0; j < 8; j++) {
      float v = w[(kb + j) * 128 + n];
      _Float16 h = (_Float16)v;
      hi[j] = h;
      lo[j] = (_Float16)(v - (float)h);
    }
    int o = ((t16 * 4 + ks) * 64 + lane) * 8;
    *(h8*)(img + o) = hi;
    *(h8*)(img + 16384 + o) = lo;
  } else {
    int l = blockIdx.x - 12;
    const int* src = src_all + (size_t)l * NE;
    __shared__ int cnt[PP];        // 32 KB
    __shared__ int bsum[1024];
#pragma unroll
    for (int j = 0; j < 8; j++) cnt[t + j * 1024] = 0;
    __syncthreads();
#pragma unroll 4
    for (int j = 0; j < 64; j++) {
      int q = src[j * 1024 + t];
      atomicAdd(&cnt[q], 1);
    }
    __syncthreads();
    int loc[8];
    int s = 0;
#pragma unroll
    for (int j = 0; j < 8; j++) { loc[j] = cnt[t * 8 + j]; s += loc[j]; }
    bsum[t] = s;
    __syncthreads();
    for (int off = 1; off < 1024; off <<= 1) {
      int v = (t >= off) ? bsum[t - off] : 0;
      __syncthreads();
      bsum[t] += v;
      __syncthreads();
    }
    int run = (t == 0) ? 0 : bsum[t - 1];
#pragma unroll
    for (int j = 0; j < 8; j++) {
      offs[l * (PP + 1) + t * 8 + j] = run;
      cnt[t * 8 + j] = run;
      run += loc[j];
    }
    if (t == 1023) offs[l * (PP + 1) + PP] = run;
    __syncthreads();
#pragma unroll 4
    for (int j = 0; j < 64; j++) {
      int e = j * 1024 + t;
      int q = src[e];
      int pos = atomicAdd(&cnt[q], 1);
      edges[(size_t)l * NE + pos] = e >> 3;
    }
  }
}

// ---------------- Node transform + fused step-0 of both directions ----------------
// h = relu(x@w1+b1)@w2 + b2. Blocks 0..127 (level 0) / 1920..2047 (level 15)
// additionally emit u0 = relu(upd_b)+h into out and m0 = relu(u0@pre_w+pre_b).
__global__ __launch_bounds__(512, 4) void nt_kernel(
    const float* __restrict__ x,
    const _Float16* __restrict__ w1img, const float* __restrict__ b1,
    const _Float16* __restrict__ w2img, const float* __restrict__ b2,
    float* __restrict__ hout,
    const float* __restrict__ f_upd_b, const _Float16* __restrict__ f_pre_img,
    const float* __restrict__ f_pre_b,
    const float* __restrict__ b_upd_b, const _Float16* __restrict__ b_pre_img,
    const float* __restrict__ b_pre_b,
    _Float16* __restrict__ mf0, _Float16* __restrict__ mb0,
    float* __restrict__ out) {
  __shared__ __align__(16) _Float16 abuf[8192];   // 16 KB f16 A
  __shared__ __align__(16) float dbuf[8192];      // 32 KB D-scratch
  int tid = threadIdx.x;
  int lane = tid & 63, wv = tid >> 6;             // wv = col-tile 0..7
  int c4 = tid & 31, rg4 = (tid >> 5) * 4;        // rows 0..60
  size_t base = (size_t)blockIdx.x * 64;

  h8 Bh[4], Bl[4];
  load_bfrags1(w1img, wv, lane, Bh, Bl);

#pragma unroll
  for (int j = 0; j < 4; j++) {
    int s = tid + j * 512;
    float4 v = ((const float4*)(x + base * 128))[s];
    hstore4(abuf, s >> 5, (s & 31) * 4, v);
  }
  __syncthreads();

  f4v acc[4];
#pragma unroll
  for (int rt = 0; rt < 4; rt++) acc[rt] = gemm_rt(abuf, Bh, Bl, rt * 16, lane);
  {
    int r16 = lane & 15, kb = lane >> 4;
    int col = wv * 16 + r16;
    float b = b1[col];
#pragma unroll
    for (int rt = 0; rt < 4; rt++)
#pragma unroll
      for (int r = 0; r < 4; r++)
        dbuf[uswz(rt * 16 + kb * 4 + r, col)] = fmaxf(acc[rt][r] + b, 0.f);
  }
  load_bfrags1(w2img, wv, lane, Bh, Bl);
  __syncthreads();

  float4 uu[4];
#pragma unroll
  for (int i = 0; i < 4; i++) uu[i] = *(const float4*)(dbuf + uswz(rg4 + i, c4 * 4));
#pragma unroll
  for (int i = 0; i < 4; i++) hstore4(abuf, rg4 + i, c4 * 4, uu[i]);
  __syncthreads();

#pragma unroll
  for (int rt = 0; rt < 4; rt++) acc[rt] = gemm_rt(abuf, Bh, Bl, rt * 16, lane);
  {
    int r16 = lane & 15, kb = lane >> 4;
    int col = wv * 16 + r16;
    float b = b2[col];
#pragma unroll
    for (int rt = 0; rt < 4; rt++)
#pragma unroll
      for (int r = 0; r < 4; r++)
        dbuf[uswz(rt * 16 + kb * 4 + r, col)] = acc[rt][r] + b;
  }
  __syncthreads();
#pragma unroll
  for (int i = 0; i < 4; i++)
    st4(hout + (base + rg4 + i) * 128 + c4 * 4, *(const float4*)(dbuf + uswz(rg4 + i, c4 * 4)));

  // ---- fused step 0: level-0 (fwd) / level-15 (bwd) blocks ----
  bool lvl0 = (blockIdx.x < 128);
  bool lvl15 = (blockIdx.x >= 1920);
  if (lvl0 || lvl15) {
    const float* ub = lvl0 ? f_upd_b : b_upd_b;
    const _Float16* pimg = lvl0 ? f_pre_img : b_pre_img;
    const float* pb = lvl0 ? f_pre_b : b_pre_b;
    _Float16* mdst = lvl0 ? mf0 : mb0;
    int coloff = lvl0 ? 0 : 128;
    size_t lbase = lvl0 ? 0 : (size_t)15 * PP;   // node base of the level

    float4 bv = ld4(ub + c4 * 4);
    float4 rb;
    rb.x = fmaxf(bv.x, 0.f); rb.y = fmaxf(bv.y, 0.f);
    rb.z = fmaxf(bv.z, 0.f); rb.w = fmaxf(bv.w, 0.f);
    float4 u[4];
#pragma unroll
    for (int i = 0; i < 4; i++) {
      int row = rg4 + i;
      float4 hv = *(const float4*)(dbuf + uswz(row, c4 * 4));   // dbuf still holds h
      u[i].x = hv.x + rb.x; u[i].y = hv.y + rb.y;
      u[i].z = hv.z + rb.z; u[i].w = hv.w + rb.w;
      st4(out + (base + row) * 256 + coloff + c4 * 4, u[i]);
      hstore4(abuf, row, c4 * 4, u[i]);                          // safe: abuf reads done
    }
    load_bfrags1(pimg, wv, lane, Bh, Bl);
    __syncthreads();
#pragma unroll
    for (int rt = 0; rt < 4; rt++) acc[rt] = gemm_rt(abuf, Bh, Bl, rt * 16, lane);
    {
      int r16 = lane & 15, kb = lane >> 4;
      int col = wv * 16 + r16;
      float b = pb[col];
#pragma unroll
      for (int rt = 0; rt < 4; rt++)
#pragma unroll
        for (int r = 0; r < 4; r++) {
          int row = rt * 16 + kb * 4 + r;
          float m = fmaxf(acc[rt][r] + b, 0.f);
          mdst[(base + row - lbase) * 128 + col] = (_Float16)m;
        }
    }
  }
}

// ---------------- Fused message-passing step (s in 1..15) ----------------
// grid = 512: blocks 0..255 = forward level s, 256..511 = reverse level 15-s.
// 512 threads (8 waves = 8 col-strips of 16), 32-row tiles.
// Direct D-layout epilogues: 2 barriers, no f32 scratch. LDS 16 KB.
__global__ __launch_bounds__(512, 4) void mp_step(
    const float* __restrict__ h,
    const int* __restrict__ src_all,
    const int* __restrict__ offs,
    const int* __restrict__ edges,
    const _Float16* __restrict__ fw_upd_img, const float* __restrict__ fw_upd_b,
    const _Float16* __restrict__ fw_pre_img, const float* __restrict__ fw_pre_b,
    const _Float16* __restrict__ bw_upd_img, const float* __restrict__ bw_upd_b,
    const _Float16* __restrict__ bw_pre_img, const float* __restrict__ bw_pre_b,
    const _Float16* __restrict__ mf_in, _Float16* __restrict__ mf_out,
    const _Float16* __restrict__ mb_in, _Float16* __restrict__ mb_out,
    float* __restrict__ out, int step) {
  __shared__ __align__(16) _Float16 abuf0[4096];  // 8 KB: gather z (f16)
  __shared__ __align__(16) _Float16 abuf1[4096];  // 8 KB: u (f16)
  int tid = threadIdx.x;
  int lane = tid & 63, wv = tid >> 6;             // wv = col-tile 0..7
  int c4 = tid & 31, rg2 = (tid >> 5) * 2;        // rows 0..30, 2 per thread
  int r16 = lane & 15, kb = lane >> 4;
  int colg = wv * 16 + r16;                       // this lane's D column
  bool is_fwd = blockIdx.x < 256;
  int tile = (blockIdx.x & 255) * 32;
  int level = is_fwd ? step : 15 - step;
  const _Float16* upd_img = is_fwd ? fw_upd_img : bw_upd_img;
  const float* upd_b = is_fwd ? fw_upd_b : bw_upd_b;
  const _Float16* pre_img = is_fwd ? fw_pre_img : bw_pre_img;
  const float* pre_b = is_fwd ? fw_pre_b : bw_pre_b;
  const _Float16* m_in = is_fwd ? mf_in : mb_in;
  _Float16* m_out      = is_fwd ? mf_out : mb_out;
  bool has_mout = (step < 15);
  int col_off = is_fwd ? 0 : 128;

  // B-fragments for the update GEMM: latency overlaps the gather.
  h8 BhU[4], BlU[4];
  load_bfrags1(upd_img, wv, lane, BhU, BlU);

  // ---- phase A: gather z (f16 messages, f32 accumulate) -> abuf0 ----
  if (is_fwd) {
    const int* src = src_all + (size_t)(step - 1) * NE;
#pragma unroll
    for (int i = 0; i < 2; i++) {
      int r = rg2 + i;
      int p = tile + r;
      const int4* sp = (const int4*)(src + p * 8);
      int4 s0 = sp[0], s1 = sp[1];
      h4 v0 = *(const h4*)(m_in + (size_t)s0.x * 128 + c4 * 4);
      h4 v1 = *(const h4*)(m_in + (size_t)s0.y * 128 + c4 * 4);
      h4 v2 = *(const h4*)(m_in + (size_t)s0.z * 128 + c4 * 4);
      h4 v3 = *(const h4*)(m_in + (size_t)s0.w * 128 + c4 * 4);
      h4 v4 = *(const h4*)(m_in + (size_t)s1.x * 128 + c4 * 4);
      h4 v5 = *(const h4*)(m_in + (size_t)s1.y * 128 + c4 * 4);
      h4 v6 = *(const h4*)(m_in + (size_t)s1.z * 128 + c4 * 4);
      h4 v7 = *(const h4*)(m_in + (size_t)s1.w * 128 + c4 * 4);
      float4 a;
      a.x = (((float)v0[0] + (float)v1[0]) + ((float)v2[0] + (float)v3[0])) +
            (((float)v4[0] + (float)v5[0]) + ((float)v6[0] + (float)v7[0]));
      a.y = (((float)v0[1] + (float)v1[1]) + ((float)v2[1] + (float)v3[1])) +
            (((float)v4[1] + (float)v5[1]) + ((float)v6[1] + (float)v7[1]));
      a.z = (((float)v0[2] + (float)v1[2]) + ((float)v2[2] + (float)v3[2])) +
            (((float)v4[2] + (float)v5[2]) + ((float)v6[2] + (float)v7[2]));
      a.w = (((float)v0[3] + (float)v1[3]) + ((float)v2[3] + (float)v3[3])) +
            (((float)v4[3] + (float)v5[3]) + ((float)v6[3] + (float)v7[3]));
      a.x *= 0.125f; a.y *= 0.125f; a.z *= 0.125f; a.w *= 0.125f;
      hstore4(abuf0, r, c4 * 4, a);
    }
  } else {
    const int* off_l = offs + level * (PP + 1);
    const int* ep = edges + level * NE;
#pragma unroll
    for (int i = 0; i < 2; i++) {
      int r = rg2 + i;
      int q = tile + r;
      int e0 = off_l[q], e1 = off_l[q + 1];
      float4 a = {0.f, 0.f, 0.f, 0.f};
      int idx = e0;
      for (; idx + 4 <= e1; idx += 4) {
        int p0 = ep[idx], p1 = ep[idx + 1], p2 = ep[idx + 2], p3 = ep[idx + 3];
        h4 v0 = *(const h4*)(m_in + (size_t)p0 * 128 + c4 * 4);
        h4 v1 = *(const h4*)(m_in + (size_t)p1 * 128 + c4 * 4);
        h4 v2 = *(const h4*)(m_in + (size_t)p2 * 128 + c4 * 4);
        h4 v3 = *(const h4*)(m_in + (size_t)p3 * 128 + c4 * 4);
        a.x += ((float)v0[0] + (float)v1[0]) + ((float)v2[0] + (float)v3[0]);
        a.y += ((float)v0[1] + (float)v1[1]) + ((float)v2[1] + (float)v3[1]);
        a.z += ((float)v0[2] + (float)v1[2]) + ((float)v2[2] + (float)v3[2]);
        a.w += ((float)v0[3] + (float)v1[3]) + ((float)v2[3] + (float)v3[3]);
      }
      for (; idx < e1; idx++) {
        int p = ep[idx];
        h4 v = *(const h4*)(m_in + (size_t)p * 128 + c4 * 4);
        a.x += (float)v[0]; a.y += (float)v[1]; a.z += (float)v[2]; a.w += (float)v[3];
      }
      float inv = (e1 > e0) ? 1.0f / (float)(e1 - e0) : 0.f;
      a.x *= inv; a.y *= inv; a.z *= inv; a.w *= inv;
      hstore4(abuf0, r, c4 * 4, a);
    }
  }
  __syncthreads();                                // bar1: z ready

  // ---- phase B: u = relu(z@upd_w + upd_b) + h; direct D-layout epilogue ----
  f4v acc[2];
#pragma unroll
  for (int rt = 0; rt < 2; rt++) acc[rt] = gemm_rt(abuf0, BhU, BlU, rt * 16, lane);
  {
    float ubs = upd_b[colg];
#pragma unroll
    for (int rt = 0; rt < 2; rt++)
#pragma unroll
      for (int r = 0; r < 4; r++) {
        int row = rt * 16 + kb * 4 + r;
        size_t n = (size_t)level * PP + tile + row;
        float hv = h[n * 128 + colg];
        float uval = fmaxf(acc[rt][r] + ubs, 0.f) + hv;
        out[n * 256 + col_off + colg] = uval;
        abuf1[swz(row, colg)] = (_Float16)uval;
      }
  }

  // ---- phase C: m_out = relu(u @ pre_w + pre_b), direct D-layout f16 store ----
  if (has_mout) {
    h8 BhP[4], BlP[4];
    load_bfrags1(pre_img, wv, lane, BhP, BlP);
    __syncthreads();                              // bar2: u ready
#pragma unroll
    for (int rt = 0; rt < 2; rt++) acc[rt] = gemm_rt(abuf1, BhP, BlP, rt * 16, lane);
    float pbs = pre_b[colg];
#pragma unroll
    for (int rt = 0; rt < 2; rt++)
#pragma unroll
      for (int r = 0; r < 4; r++) {
        int row = rt * 16 + kb * 4 + r;
        float m = fmaxf(acc[rt][r] + pbs, 0.f);
        m_out[(size_t)(tile + row) * 128 + colg] = (_Float16)m;
      }
  }
}

extern "C" void kernel_launch(void* const* d_in, const int* in_sizes, int n_in,
                              void* d_out, int out_size, void* d_ws, size_t ws_size,
                              hipStream_t stream) {
  const float* x      = (const float*)d_in[0];
  const int*   src    = (const int*)d_in[1];
  const float* nt_w1  = (const float*)d_in[2];
  const float* nt_b1  = (const float*)d_in[3];
  const float* nt_w2  = (const float*)d_in[4];
  const float* nt_b2  = (const float*)d_in[5];
  const float* f_pre_w = (const float*)d_in[6];
  const float* f_pre_b = (const float*)d_in[7];
  const float* f_upd_w = (const float*)d_in[8];
  const float* f_upd_b = (const float*)d_in[9];
  const float* b_pre_w = (const float*)d_in[10];
  const float* b_pre_b = (const float*)d_in[11];
  const float* b_upd_w = (const float*)d_in[12];
  const float* b_upd_b = (const float*)d_in[13];
  float* out = (float*)d_out;

  float* wsf = (float*)d_ws;
  float* h   = wsf;                                  // NN*DD f32
  _Float16* mf0 = (_Float16*)(h + (size_t)NN * DD);  // PP*DD f16 each
  _Float16* mf1 = mf0 + (size_t)PP * DD;
  _Float16* mb0 = mf1 + (size_t)PP * DD;
  _Float16* mb1 = mb0 + (size_t)PP * DD;
  int* offs   = (int*)(mb1 + (size_t)PP * DD);       // NLVL*(PP+1)
  int* edges  = offs + NLVL * (PP + 1);              // NLVL*NE

  // fragment-ordered f16 hi/lo weight images (32768 halves = 64KB each)
  uintptr_t ip = (uintptr_t)(edges + (size_t)NLVL * NE);
  ip = (ip + 15) & ~(uintptr_t)15;
  _Float16* img = (_Float16*)ip;
  _Float16* i_ntw1 = img;                 // mat 0
  _Float16* i_ntw2 = img + 32768;         // mat 1
  _Float16* i_fupd = img + 2 * 32768;     // mat 2
  _Float16* i_fpre = img + 3 * 32768;     // mat 3
  _Float16* i_bupd = img + 4 * 32768;     // mat 4
  _Float16* i_bpre = img + 5 * 32768;     // mat 5

  setup_kernel<<<27, 1024, 0, stream>>>(nt_w1, nt_w2, f_upd_w, f_pre_w, b_upd_w, b_pre_w,
                                        img, src, offs, edges);
  nt_kernel<<<NN / 64, 512, 0, stream>>>(x, i_ntw1, nt_b1, i_ntw2, nt_b2, h,
                                         f_upd_b, i_fpre, f_pre_b,
                                         b_upd_b, i_bpre, b_pre_b,
                                         mf0, mb0, out);

  for (int s = 1; s < 16; s++) {
    const _Float16* mf_in = (s & 1) ? mf0 : mf1;
    _Float16* mf_out      = (s & 1) ? mf1 : mf0;
    const _Float16* mb_in = (s & 1) ? mb0 : mb1;
    _Float16* mb_out      = (s & 1) ? mb1 : mb0;
    mp_step<<<512, 512, 0, stream>>>(h, src, offs, edges,
                                     i_fupd, f_upd_b, i_fpre, f_pre_b,
                                     i_bupd, b_upd_b, i_bpre, b_pre_b,
                                     mf_in, mf_out, mb_in, mb_out, out, s);
  }
}